// Round 17
// baseline (248.054 us; speedup 1.0000x reference)
//
#include <hip/hip_runtime.h>
#include <math.h>
#include <float.h>

#define PSZ 256
#define NPATCH 127
#define L 16129            // 127*127
#define KTOP 4
#define TMAIN 256
#define RPT 2              // rows per thread (64-VGPR budget is a hard platform limit)
#define ROWS_PER_BLOCK (TMAIN * RPT)   // 512
#define NROWBLK 32                     // 32*512 = 16384 >= L
#define NS 32
#define SEGLEN 512                     // 32*512 = 16384 >= L; 31/32 segments have no tail
#define MSTRIDE 512                    // LDS stride (broadcast reads -> banks irrelevant)
#define ROWPAD 16384
#define GRP 32                         // tournament group size (r17: 16->32 halves insert cost)
#define APAD 12                        // A/BT row stride (16B-aligned float4 rows)
#define NCHUNK 56                      // mean-partial chunks per combo (36*56 = 2016 blocks)

// ---- workspace layout (float elements) ----
static constexpr size_t OFF_REFG = 0;                          // [2][256][256]
static constexpr size_t OFF_XG   = OFF_REFG + 2 * PSZ * PSZ;   // 131072
static constexpr size_t OFF_MUI  = OFF_XG   + 2 * PSZ * PSZ;   // [18] (legacy, unused)
static constexpr size_t OFF_MUR  = OFF_MUI  + 20;
static constexpr size_t OFF_A    = OFF_MUR  + 20;              // [2][L][APAD] input_norm (padded)
static constexpr size_t OFF_B    = OFF_A    + (size_t)2 * L * APAD;  // [2][9][L] ref_norm (p-major)
static constexpr size_t OFF_BT   = OFF_B    + 290324;          // [2][L][APAD] ref_norm (padded)
static constexpr size_t OFF_IDX  = OFF_BT   + (size_t)2 * L * APAD;  // [2][L][4] final idx (int)
static constexpr size_t OFF_PV   = OFF_IDX  + 2 * L * 4;       // [2][NS][ROWPAD][4] group-max vals
static constexpr size_t OFF_PI   = OFF_PV   + (size_t)2 * NS * ROWPAD * 4;  // group bases (int)
static constexpr size_t OFF_PAR  = OFF_PV;  // 36*56 doubles alias PV (consumed by k5 before k6 writes PV)
// end ~= 9.84M floats (39.4 MB) <= 41.07 MB proven present.

// insert (rm, gb) into sorted-desc; strict > keeps earlier entry on ties
// (candidates arrive in ascending gb). Each group inserted exactly once.
__device__ __forceinline__ void insg(float rm, int gb,
    float& g0, float& g1, float& g2, float& g3,
    int& i0, int& i1, int& i2, int& i3) {
  bool c0 = rm > g0, c1 = rm > g1, c2 = rm > g2, c3 = rm > g3;
  g3 = c2 ? g2 : (c3 ? rm : g3);  i3 = c2 ? i2 : (c3 ? gb : i3);
  g2 = c1 ? g1 : (c2 ? rm : g2);  i2 = c1 ? i1 : (c2 ? gb : i2);
  g1 = c0 ? g0 : (c1 ? rm : g1);  i1 = c0 ? i0 : (c1 ? gb : i1);
  g0 = c0 ? rm : g0;              i0 = c0 ? gb : i0;
}

// composite-order insert: (v desc, m asc). NOT duplicate-safe -- callers must
// feed DISTINCT (v,m) candidates (k7's rescan ranges are disjoint: round-9 fix).
__device__ __forceinline__ void ins4c(float v, int m,
    float& v0, float& v1, float& v2, float& v3,
    int& x0, int& x1, int& x2, int& x3) {
  bool c0 = (v > v0) || (v == v0 && m < x0);
  bool c1 = (v > v1) || (v == v1 && m < x1);
  bool c2 = (v > v2) || (v == v2 && m < x2);
  bool c3 = (v > v3) || (v == v3 && m < x3);
  v3 = c2 ? v2 : (c3 ? v : v3);  x3 = c2 ? x2 : (c3 ? m : x3);
  v2 = c1 ? v1 : (c2 ? v : v2);  x2 = c1 ? x1 : (c2 ? m : x2);
  v1 = c0 ? v0 : (c1 ? v : v1);  x1 = c0 ? x0 : (c1 ? m : x1);
  v0 = c0 ? v : v0;              x0 = c0 ? m : x0;
}

// k12 (fused k1+k2), 4 consecutive pixels/thread via float4:
// XG = 3x3 clipped-window max of channel-max(x) - channel-min(x);
// REFG = channel-mean(ref); copy x -> out[:, :3].
__global__ void k12_gray(const float* __restrict__ x, const float* __restrict__ ref,
                         float* __restrict__ ws, float* __restrict__ out) {
  __shared__ float sm[34][35];
  int tile = blockIdx.x & 63;        // 8x8 tiles of 32x32
  int b = blockIdx.x >> 6;
  int ty0 = (tile >> 3) << 5, tx0 = (tile & 7) << 5;
  const float* xb = x + (size_t)b * 3 * 65536;
  const float* rb = ref + (size_t)b * 3 * 65536;
  for (int hid = threadIdx.x; hid < 34 * 34; hid += 256) {
    int hy = hid / 34, hx = hid % 34;
    int gy = ty0 + hy - 1, gx = tx0 + hx - 1;
    float m = -FLT_MAX;
    if (gy >= 0 && gy < 256 && gx >= 0 && gx < 256) {
      int pix = gy * 256 + gx;
      m = fmaxf(fmaxf(xb[pix], xb[65536 + pix]), xb[131072 + pix]);
    }
    sm[hy][hx] = m;
  }
  __syncthreads();
  int t4 = threadIdx.x * 4;          // 256 threads x 4 px = 1024 px
  int iy = t4 >> 5, ix = t4 & 31;
  int gy = ty0 + iy, gx = tx0 + ix;
  int pix = gy * 256 + gx;           // multiple of 4 -> 16B-aligned
  float4 c0 = *(const float4*)(xb + pix);
  float4 c1 = *(const float4*)(xb + 65536 + pix);
  float4 c2 = *(const float4*)(xb + 131072 + pix);
  float4 r0 = *(const float4*)(rb + pix);
  float4 r1 = *(const float4*)(rb + 65536 + pix);
  float4 r2 = *(const float4*)(rb + 131072 + pix);
  float cm[7];
#pragma unroll
  for (int c = 0; c < 7; ++c)
    cm[c] = fmaxf(fmaxf(sm[iy][ix + c], sm[iy + 1][ix + c]), sm[iy + 2][ix + c]);
  float cc0[4] = {c0.x, c0.y, c0.z, c0.w};
  float cc1[4] = {c1.x, c1.y, c1.z, c1.w};
  float cc2[4] = {c2.x, c2.y, c2.z, c2.w};
  float rr0[4] = {r0.x, r0.y, r0.z, r0.w};
  float rr1[4] = {r1.x, r1.y, r1.z, r1.w};
  float rr2[4] = {r2.x, r2.y, r2.z, r2.w};
  float xgv[4], rgv[4];
#pragma unroll
  for (int k = 0; k < 4; ++k) {
    float cmin = fminf(fminf(cc0[k], cc1[k]), cc2[k]);
    float mx = fmaxf(fmaxf(cm[k], cm[k + 1]), cm[k + 2]);
    xgv[k] = mx - cmin;
    rgv[k] = (rr0[k] + rr1[k] + rr2[k]) / 3.0f;
  }
  size_t id0 = ((size_t)b << 16) + pix;
  *(float4*)(ws + OFF_XG + id0) = make_float4(xgv[0], xgv[1], xgv[2], xgv[3]);
  *(float4*)(ws + OFF_REFG + id0) = make_float4(rgv[0], rgv[1], rgv[2], rgv[3]);
  float* ob = out + (size_t)b * 7 * 65536 + pix;
  *(float4*)(ob) = c0;
  *(float4*)(ob + 65536) = c1;
  *(float4*)(ob + 131072) = c2;
}

// k4a: per-(combo,chunk) f64 partial sums. combo = which*18 + b*9 + p (36),
// 56 chunks of 288(+1) patches -> 2016 blocks. Deterministic fixed-order tree;
// partials land in OFF_PAR (aliases PV, consumed by k5 before k6 overwrites).
__global__ void k4a_partial(float* __restrict__ ws) {
  __shared__ double smd[TMAIN];
  int cmb = blockIdx.x / NCHUNK, chunk = blockIdx.x % NCHUNK;
  int which = cmb / 18, rest = cmb % 18;
  int b = rest / 9, p = rest % 9;
  int di = p / 3, dj = p % 3;
  const float* g = ws + (which ? OFF_REFG : OFF_XG) + ((size_t)b << 16);
  int l0 = chunk * 288;
  int lend = (chunk == NCHUNK - 1) ? L : l0 + 288;
  double s = 0.0;
  for (int l = l0 + (int)threadIdx.x; l < lend; l += TMAIN) {
    int i = l / NPATCH, j = l % NPATCH;
    s += (double)g[(2 * i + di) * PSZ + 2 * j + dj];
  }
  smd[threadIdx.x] = s;
  __syncthreads();
  for (int st = 128; st > 0; st >>= 1) {
    if ((int)threadIdx.x < st) smd[threadIdx.x] += smd[threadIdx.x + st];
    __syncthreads();
  }
  if (threadIdx.x == 0)
    ((double*)(ws + OFF_PAR))[cmb * NCHUNK + chunk] = smd[0];
}

// k5: prologue reduces the 36x56 partials to means (36 threads, LDS
// broadcast); then per l compute patch values + uncentered norms, then
// A[b][l][APAD] = (ip - muI)/nI ; B[b][9][L] and BT[b][l][APAD] = (rp - muR)/nR.
__global__ void k5_norm(float* __restrict__ ws) {
  __shared__ float smu[40];
  if (threadIdx.x < 36) {
    const double* par = (const double*)(ws + OFF_PAR);
    double s = 0.0;
    for (int c = 0; c < NCHUNK; ++c) s += par[threadIdx.x * NCHUNK + c];
    smu[threadIdx.x] = (float)(s / (double)L);
  }
  __syncthreads();
  int id = blockIdx.x * 256 + threadIdx.x;
  if (id >= 2 * L) return;
  int b = id / L, l = id % L;
  int i = l / NPATCH, j = l % NPATCH;
  const float* xg = ws + OFF_XG + ((size_t)b << 16);
  const float* rg = ws + OFF_REFG + ((size_t)b << 16);
  float vi[9], vr[9];
  float si = 0.f, sr = 0.f;
#pragma unroll
  for (int p = 0; p < 9; ++p) {
    int di = p / 3, dj = p % 3;
    vi[p] = xg[(2 * i + di) * PSZ + 2 * j + dj];
    vr[p] = rg[(2 * i + di) * PSZ + 2 * j + dj];
    si += vi[p] * vi[p];
    sr += vr[p] * vr[p];
  }
  float ni = sqrtf(si), nr = sqrtf(sr);
  float an[12], btn[12];
#pragma unroll
  for (int p = 0; p < 9; ++p) {
    float mi = smu[b * 9 + p];          // which=0 (input)
    float mr = smu[18 + b * 9 + p];     // which=1 (ref)
    float bn = (vr[p] - mr) / nr;
    an[p] = (vi[p] - mi) / ni;
    btn[p] = bn;
    ws[OFF_B + ((size_t)b * 9 + p) * L + l] = bn;
  }
  an[9] = an[10] = an[11] = 0.f;
  btn[9] = btn[10] = btn[11] = 0.f;
  float4* Ap4 = (float4*)(ws + OFF_A + (size_t)(b * L + l) * APAD);
  Ap4[0] = make_float4(an[0], an[1], an[2], an[3]);
  Ap4[1] = make_float4(an[4], an[5], an[6], an[7]);
  Ap4[2] = make_float4(an[8], an[9], an[10], an[11]);
  float4* Bt4 = (float4*)(ws + OFF_BT + (size_t)(b * L + l) * APAD);
  Bt4[0] = make_float4(btn[0], btn[1], btn[2], btn[3]);
  Bt4[1] = make_float4(btn[4], btn[5], btn[6], btn[7]);
  Bt4[2] = make_float4(btn[8], btn[9], btn[10], btn[11]);
}

// k6: r13 structure with GRP=32 (r17): one 19-op insert per 32 m per row
// instead of per 16 -- ~7% fewer VALU insts; DS stream and register
// working set unchanged. Everything else frozen (LDS broadcast, RPT=2,
// SEGLEN=512; pk-math r8, RPT=4 r11, SMEM r12, fn-pointer r15 all regressed).
// grid: 2 x 32(rowblk) x 32(seg) = 2048 blocks (8/CU), 256 threads.
__global__ __launch_bounds__(TMAIN, 2) void k6_topk(float* __restrict__ ws) {
  __shared__ float lds[9 * MSTRIDE];  // 18432 B

  int bid = blockIdx.x;
  int seg = bid & (NS - 1);
  int rowblk = (bid >> 5) & (NROWBLK - 1);
  int b = bid >> 10;
  int m0 = seg << 9;
  int mend = m0 + SEGLEN;
  if (mend > L) mend = L;
  int mlen = mend - m0;

  const float* Bg = ws + OFF_B + (size_t)b * 9 * L + m0;
  for (int p = 0; p < 9; ++p)
    for (int mm = threadIdx.x; mm < mlen; mm += TMAIN)
      lds[p * MSTRIDE + mm] = Bg[(size_t)p * L + mm];
  __syncthreads();

  int row0 = rowblk * ROWS_PER_BLOCK + threadIdx.x * RPT;
  int r0 = row0 < L - 1 ? row0 : L - 1;
  int r1 = row0 + 1 < L - 1 ? row0 + 1 : L - 1;
  float a0[9], a1[9];
  {
    const float4* Ap0 = (const float4*)(ws + OFF_A + ((size_t)b * L + r0) * APAD);
    const float4* Ap1 = (const float4*)(ws + OFF_A + ((size_t)b * L + r1) * APAD);
    float4 u0 = Ap0[0], u1 = Ap0[1], u2 = Ap0[2];
    float4 w0 = Ap1[0], w1 = Ap1[1], w2 = Ap1[2];
    a0[0] = u0.x; a0[1] = u0.y; a0[2] = u0.z; a0[3] = u0.w;
    a0[4] = u1.x; a0[5] = u1.y; a0[6] = u1.z; a0[7] = u1.w; a0[8] = u2.x;
    a1[0] = w0.x; a1[1] = w0.y; a1[2] = w0.z; a1[3] = w0.w;
    a1[4] = w1.x; a1[5] = w1.y; a1[6] = w1.z; a1[7] = w1.w; a1[8] = w2.x;
  }

  float g00 = -FLT_MAX, g01 = g00, g02 = g00, g03 = g00;
  float g10 = g00, g11 = g00, g12 = g00, g13 = g00;
  int i00 = 0, i01 = 0, i02 = 0, i03 = 0;
  int i10 = 0, i11 = 0, i12 = 0, i13 = 0;

  int nfull = mlen >> 5;  // full groups of 32 (== 16 for segs 0..30)
  for (int g = 0; g < nfull; ++g) {
    int mm = g << 5;
    float rm0 = -FLT_MAX, rm1 = -FLT_MAX;
#pragma unroll
    for (int q = 0; q < 8; ++q) {
      float s00, s01, s02, s03, s10, s11, s12, s13;
#pragma unroll
      for (int p = 0; p < 9; ++p) {
        const float4 bq = *reinterpret_cast<const float4*>(&lds[p * MSTRIDE + mm + q * 4]);
        if (p == 0) {
          s00 = a0[0] * bq.x; s01 = a0[0] * bq.y; s02 = a0[0] * bq.z; s03 = a0[0] * bq.w;
          s10 = a1[0] * bq.x; s11 = a1[0] * bq.y; s12 = a1[0] * bq.z; s13 = a1[0] * bq.w;
        } else {
          s00 = fmaf(a0[p], bq.x, s00); s01 = fmaf(a0[p], bq.y, s01);
          s02 = fmaf(a0[p], bq.z, s02); s03 = fmaf(a0[p], bq.w, s03);
          s10 = fmaf(a1[p], bq.x, s10); s11 = fmaf(a1[p], bq.y, s11);
          s12 = fmaf(a1[p], bq.z, s12); s13 = fmaf(a1[p], bq.w, s13);
        }
      }
      rm0 = fmaxf(rm0, fmaxf(fmaxf(s00, s01), fmaxf(s02, s03)));
      rm1 = fmaxf(rm1, fmaxf(fmaxf(s10, s11), fmaxf(s12, s13)));
    }
    int gb = m0 + mm;
    insg(rm0, gb, g00, g01, g02, g03, i00, i01, i02, i03);
    insg(rm1, gb, g10, g11, g12, g13, i10, i11, i12, i13);
  }
  // tail (< 32 m, only the last segment has one; in-segment only)
  int tb = nfull << 5;
  if (tb < mlen) {
    float rt0 = -FLT_MAX, rt1 = -FLT_MAX;
    for (int mm = tb; mm < mlen; ++mm) {
      float bb = lds[mm];
      float sv0 = a0[0] * bb, sv1 = a1[0] * bb;
#pragma unroll
      for (int p = 1; p < 9; ++p) {
        bb = lds[p * MSTRIDE + mm];
        sv0 = fmaf(a0[p], bb, sv0); sv1 = fmaf(a1[p], bb, sv1);
      }
      rt0 = fmaxf(rt0, sv0); rt1 = fmaxf(rt1, sv1);
    }
    insg(rt0, m0 + tb, g00, g01, g02, g03, i00, i01, i02, i03);
    insg(rt1, m0 + tb, g10, g11, g12, g13, i10, i11, i12, i13);
  }

  int* wsi = (int*)ws;
  if (row0 < L) {
    size_t base = (((size_t)b * NS + seg) * ROWPAD + row0) * 4;
    ws[OFF_PV + base + 0] = g00; ws[OFF_PV + base + 1] = g01;
    ws[OFF_PV + base + 2] = g02; ws[OFF_PV + base + 3] = g03;
    wsi[OFF_PI + base + 0] = i00; wsi[OFF_PI + base + 1] = i01;
    wsi[OFF_PI + base + 2] = i02; wsi[OFF_PI + base + 3] = i03;
  }
  if (row0 + 1 < L) {
    size_t base = (((size_t)b * NS + seg) * ROWPAD + row0 + 1) * 4;
    ws[OFF_PV + base + 0] = g10; ws[OFF_PV + base + 1] = g11;
    ws[OFF_PV + base + 2] = g12; ws[OFF_PV + base + 3] = g13;
    wsi[OFF_PI + base + 0] = i10; wsi[OFF_PI + base + 1] = i11;
    wsi[OFF_PI + base + 2] = i12; wsi[OFF_PI + base + 3] = i13;
  }
}

// k7: per row, merge 32 segs x 4 (group-max, base) -> top-4 groups by
// (max desc, base asc), then rescan those groups (<= 4x32 m) with ranges
// CLIPPED TO THE SEGMENT END (= exactly k6's group coverage; disjoint ->
// no duplicate inserts). BT rescan reads are 3x float4.
__global__ void k7_merge(float* __restrict__ ws) {
  int id = blockIdx.x * 256 + threadIdx.x;
  if (id >= 2 * L) return;
  int b = id / L, row = id % L;
  const int* wsi_c = (const int*)ws;

  float v0 = -FLT_MAX, v1 = v0, v2 = v0, v3 = v0;
  int x0 = 0x7FFFFFFF, x1 = x0, x2 = x0, x3 = x0;
  for (int s = 0; s < NS; ++s) {
    size_t base = (((size_t)b * NS + s) * ROWPAD + row) * 4;
#pragma unroll
    for (int q = 0; q < 4; ++q) {
      float val = ws[OFF_PV + base + q];
      int gb = wsi_c[OFF_PI + base + q];
      ins4c(val, gb, v0, v1, v2, v3, x0, x1, x2, x3);
    }
  }

  float a[9];
  {
    const float4* Ap4 = (const float4*)(ws + OFF_A + ((size_t)b * L + row) * APAD);
    float4 u0 = Ap4[0], u1 = Ap4[1], u2 = Ap4[2];
    a[0] = u0.x; a[1] = u0.y; a[2] = u0.z; a[3] = u0.w;
    a[4] = u1.x; a[5] = u1.y; a[6] = u1.z; a[7] = u1.w; a[8] = u2.x;
  }

  int gbs[4] = {x0, x1, x2, x3};
  float w0 = -FLT_MAX, w1 = w0, w2 = w0, w3 = w0;
  int y0 = 0x7FFFFFFF, y1 = y0, y2 = y0, y3 = y0;
#pragma unroll
  for (int slot = 0; slot < 4; ++slot) {
    int gb = gbs[slot];
    int se = ((gb >> 9) + 1) << 9;     // owning segment's end (SEGLEN = 512)
    int ge = gb + GRP;
    if (ge > se) ge = se;
    if (ge > L) ge = L;
    for (int mm = gb; mm < ge; ++mm) {
      const float4* bt4 = (const float4*)(ws + OFF_BT + ((size_t)b * L + mm) * APAD);
      float4 b0 = bt4[0], b1 = bt4[1], b2 = bt4[2];
      float s = a[0] * b0.x;
      s = fmaf(a[1], b0.y, s); s = fmaf(a[2], b0.z, s); s = fmaf(a[3], b0.w, s);
      s = fmaf(a[4], b1.x, s); s = fmaf(a[5], b1.y, s); s = fmaf(a[6], b1.z, s);
      s = fmaf(a[7], b1.w, s); s = fmaf(a[8], b2.x, s);
      ins4c(s, mm, w0, w1, w2, w3, y0, y1, y2, y3);
    }
  }
  int* wsi = (int*)ws;
  size_t ib = OFF_IDX + (size_t)id * 4;
  wsi[ib] = y0; wsi[ib + 1] = y1; wsi[ib + 2] = y2; wsi[ib + 3] = y3;
}

// k8: fold (overlap-add); one thread = one pixel x all 4 kk (IDX row read
// once as int4), reads ref_gray directly. grid 512 blocks.
__global__ void k8_fold(const float* __restrict__ ws, float* __restrict__ out) {
  int id = blockIdx.x * 256 + threadIdx.x;
  if (id >= 2 * PSZ * PSZ) return;
  int b = id >> 16;
  int pix = id & 0xFFFF;
  int y = pix >> 8, xx = pix & 255;
  const int* wsi = (const int*)ws;
  const float* rg = ws + OFF_REFG + ((size_t)b << 16);
  float acc0 = 0.f, acc1 = 0.f, acc2 = 0.f, acc3 = 0.f;
  for (int di = 0; di < 3; ++di) {
    int yy = y - di;
    if (yy < 0 || (yy & 1) || (yy >> 1) >= NPATCH) continue;
    int i = yy >> 1;
    for (int dj = 0; dj < 3; ++dj) {
      int xc = xx - dj;
      if (xc < 0 || (xc & 1) || (xc >> 1) >= NPATCH) continue;
      int j = xc >> 1;
      int l = i * NPATCH + j;
      const int4 m4 = *(const int4*)(wsi + OFF_IDX + ((size_t)b * L + l) * 4);
      acc0 += rg[(2 * (m4.x / NPATCH) + di) * PSZ + 2 * (m4.x % NPATCH) + dj];
      acc1 += rg[(2 * (m4.y / NPATCH) + di) * PSZ + 2 * (m4.y % NPATCH) + dj];
      acc2 += rg[(2 * (m4.z / NPATCH) + di) * PSZ + 2 * (m4.z % NPATCH) + dj];
      acc3 += rg[(2 * (m4.w / NPATCH) + di) * PSZ + 2 * (m4.w % NPATCH) + dj];
    }
  }
  float* ob = out + ((size_t)b * 7 + 3) * 65536 + pix;
  ob[0] = acc0;
  ob[65536] = acc1;
  ob[2 * 65536] = acc2;
  ob[3 * 65536] = acc3;
}

extern "C" void kernel_launch(void* const* d_in, const int* in_sizes, int n_in,
                              void* d_out, int out_size, void* d_ws, size_t ws_size,
                              hipStream_t stream) {
  const float* x = (const float*)d_in[0];
  const float* ref = (const float*)d_in[1];
  float* ws = (float*)d_ws;
  float* out = (float*)d_out;

  k12_gray<<<128, 256, 0, stream>>>(x, ref, ws, out);
  k4a_partial<<<36 * NCHUNK, TMAIN, 0, stream>>>(ws);
  k5_norm<<<(2 * L + 255) / 256, 256, 0, stream>>>(ws);
  k6_topk<<<2 * NROWBLK * NS, TMAIN, 0, stream>>>(ws);
  k7_merge<<<(2 * L + 255) / 256, 256, 0, stream>>>(ws);
  k8_fold<<<(2 * PSZ * PSZ + 255) / 256, 256, 0, stream>>>(ws, out);
}

// Round 18
// 222.114 us; speedup vs baseline: 1.1168x; 1.1168x over previous
//
#include <hip/hip_runtime.h>
#include <math.h>
#include <float.h>

#define PSZ 256
#define NPATCH 127
#define L 16129            // 127*127
#define KTOP 4
#define TMAIN 256
#define RPT 2              // rows per thread (64-VGPR budget is a hard platform limit)
#define ROWS_PER_BLOCK (TMAIN * RPT)   // 512
#define NROWBLK 32                     // 32*512 = 16384 >= L
#define NS 32
#define SEGLEN 512                     // 32*512 = 16384 >= L; 31/32 segments have no tail
#define MSTRIDE 512                    // LDS stride (broadcast reads -> banks irrelevant)
#define ROWPAD 16384
#define GRP 16                         // tournament group size (GRP=32 regressed: r17)
#define APAD 12                        // A/BT row stride (16B-aligned float4 rows)
#define NCHUNK 56                      // mean-partial chunks per combo (36*56 = 2016 blocks)

// ---- workspace layout (float elements) ----
static constexpr size_t OFF_REFG = 0;                          // [2][256][256]
static constexpr size_t OFF_XG   = OFF_REFG + 2 * PSZ * PSZ;   // 131072
static constexpr size_t OFF_MUI  = OFF_XG   + 2 * PSZ * PSZ;   // [18] (legacy, unused)
static constexpr size_t OFF_MUR  = OFF_MUI  + 20;
static constexpr size_t OFF_A    = OFF_MUR  + 20;              // [2][L][APAD] input_norm (padded)
static constexpr size_t OFF_B    = OFF_A    + (size_t)2 * L * APAD;  // [2][9][L] ref_norm (p-major)
static constexpr size_t OFF_BT   = OFF_B    + 290324;          // [2][L][APAD] ref_norm (padded)
static constexpr size_t OFF_IDX  = OFF_BT   + (size_t)2 * L * APAD;  // [2][L][4] final idx (int)
static constexpr size_t OFF_PV   = OFF_IDX  + 2 * L * 4;       // [2][NS][ROWPAD][4] group-max vals
static constexpr size_t OFF_PI   = OFF_PV   + (size_t)2 * NS * ROWPAD * 4;  // group bases (int)
static constexpr size_t OFF_PAR  = OFF_PV;  // 36*56 doubles alias PV (consumed by k5 before k6 writes PV)
// end ~= 9.84M floats (39.4 MB) <= 41.07 MB proven present.

// insert (rm, gb) into sorted-desc; strict > keeps earlier entry on ties
// (candidates arrive in ascending gb). Each group inserted exactly once.
__device__ __forceinline__ void insg(float rm, int gb,
    float& g0, float& g1, float& g2, float& g3,
    int& i0, int& i1, int& i2, int& i3) {
  bool c0 = rm > g0, c1 = rm > g1, c2 = rm > g2, c3 = rm > g3;
  g3 = c2 ? g2 : (c3 ? rm : g3);  i3 = c2 ? i2 : (c3 ? gb : i3);
  g2 = c1 ? g1 : (c2 ? rm : g2);  i2 = c1 ? i1 : (c2 ? gb : i2);
  g1 = c0 ? g0 : (c1 ? rm : g1);  i1 = c0 ? i0 : (c1 ? gb : i1);
  g0 = c0 ? rm : g0;              i0 = c0 ? gb : i0;
}

// composite-order insert: (v desc, m asc). NOT duplicate-safe -- callers must
// feed DISTINCT (v,m) candidates (k7's rescan ranges are disjoint: round-9 fix).
__device__ __forceinline__ void ins4c(float v, int m,
    float& v0, float& v1, float& v2, float& v3,
    int& x0, int& x1, int& x2, int& x3) {
  bool c0 = (v > v0) || (v == v0 && m < x0);
  bool c1 = (v > v1) || (v == v1 && m < x1);
  bool c2 = (v > v2) || (v == v2 && m < x2);
  bool c3 = (v > v3) || (v == v3 && m < x3);
  v3 = c2 ? v2 : (c3 ? v : v3);  x3 = c2 ? x2 : (c3 ? m : x3);
  v2 = c1 ? v1 : (c2 ? v : v2);  x2 = c1 ? x1 : (c2 ? m : x2);
  v1 = c0 ? v0 : (c1 ? v : v1);  x1 = c0 ? x0 : (c1 ? m : x1);
  v0 = c0 ? v : v0;              x0 = c0 ? m : x0;
}

// k12 (fused k1+k2), 4 consecutive pixels/thread via float4:
// XG = 3x3 clipped-window max of channel-max(x) - channel-min(x);
// REFG = channel-mean(ref); copy x -> out[:, :3].
__global__ void k12_gray(const float* __restrict__ x, const float* __restrict__ ref,
                         float* __restrict__ ws, float* __restrict__ out) {
  __shared__ float sm[34][35];
  int tile = blockIdx.x & 63;        // 8x8 tiles of 32x32
  int b = blockIdx.x >> 6;
  int ty0 = (tile >> 3) << 5, tx0 = (tile & 7) << 5;
  const float* xb = x + (size_t)b * 3 * 65536;
  const float* rb = ref + (size_t)b * 3 * 65536;
  for (int hid = threadIdx.x; hid < 34 * 34; hid += 256) {
    int hy = hid / 34, hx = hid % 34;
    int gy = ty0 + hy - 1, gx = tx0 + hx - 1;
    float m = -FLT_MAX;
    if (gy >= 0 && gy < 256 && gx >= 0 && gx < 256) {
      int pix = gy * 256 + gx;
      m = fmaxf(fmaxf(xb[pix], xb[65536 + pix]), xb[131072 + pix]);
    }
    sm[hy][hx] = m;
  }
  __syncthreads();
  int t4 = threadIdx.x * 4;          // 256 threads x 4 px = 1024 px
  int iy = t4 >> 5, ix = t4 & 31;
  int gy = ty0 + iy, gx = tx0 + ix;
  int pix = gy * 256 + gx;           // multiple of 4 -> 16B-aligned
  float4 c0 = *(const float4*)(xb + pix);
  float4 c1 = *(const float4*)(xb + 65536 + pix);
  float4 c2 = *(const float4*)(xb + 131072 + pix);
  float4 r0 = *(const float4*)(rb + pix);
  float4 r1 = *(const float4*)(rb + 65536 + pix);
  float4 r2 = *(const float4*)(rb + 131072 + pix);
  float cm[7];
#pragma unroll
  for (int c = 0; c < 7; ++c)
    cm[c] = fmaxf(fmaxf(sm[iy][ix + c], sm[iy + 1][ix + c]), sm[iy + 2][ix + c]);
  float cc0[4] = {c0.x, c0.y, c0.z, c0.w};
  float cc1[4] = {c1.x, c1.y, c1.z, c1.w};
  float cc2[4] = {c2.x, c2.y, c2.z, c2.w};
  float rr0[4] = {r0.x, r0.y, r0.z, r0.w};
  float rr1[4] = {r1.x, r1.y, r1.z, r1.w};
  float rr2[4] = {r2.x, r2.y, r2.z, r2.w};
  float xgv[4], rgv[4];
#pragma unroll
  for (int k = 0; k < 4; ++k) {
    float cmin = fminf(fminf(cc0[k], cc1[k]), cc2[k]);
    float mx = fmaxf(fmaxf(cm[k], cm[k + 1]), cm[k + 2]);
    xgv[k] = mx - cmin;
    rgv[k] = (rr0[k] + rr1[k] + rr2[k]) / 3.0f;
  }
  size_t id0 = ((size_t)b << 16) + pix;
  *(float4*)(ws + OFF_XG + id0) = make_float4(xgv[0], xgv[1], xgv[2], xgv[3]);
  *(float4*)(ws + OFF_REFG + id0) = make_float4(rgv[0], rgv[1], rgv[2], rgv[3]);
  float* ob = out + (size_t)b * 7 * 65536 + pix;
  *(float4*)(ob) = c0;
  *(float4*)(ob + 65536) = c1;
  *(float4*)(ob + 131072) = c2;
}

// k4a: per-(combo,chunk) f64 partial sums. combo = which*18 + b*9 + p (36),
// 56 chunks of 288(+1) patches -> 2016 blocks. Deterministic fixed-order tree;
// partials land in OFF_PAR (aliases PV, consumed by k5 before k6 overwrites).
__global__ void k4a_partial(float* __restrict__ ws) {
  __shared__ double smd[TMAIN];
  int cmb = blockIdx.x / NCHUNK, chunk = blockIdx.x % NCHUNK;
  int which = cmb / 18, rest = cmb % 18;
  int b = rest / 9, p = rest % 9;
  int di = p / 3, dj = p % 3;
  const float* g = ws + (which ? OFF_REFG : OFF_XG) + ((size_t)b << 16);
  int l0 = chunk * 288;
  int lend = (chunk == NCHUNK - 1) ? L : l0 + 288;
  double s = 0.0;
  for (int l = l0 + (int)threadIdx.x; l < lend; l += TMAIN) {
    int i = l / NPATCH, j = l % NPATCH;
    s += (double)g[(2 * i + di) * PSZ + 2 * j + dj];
  }
  smd[threadIdx.x] = s;
  __syncthreads();
  for (int st = 128; st > 0; st >>= 1) {
    if ((int)threadIdx.x < st) smd[threadIdx.x] += smd[threadIdx.x + st];
    __syncthreads();
  }
  if (threadIdx.x == 0)
    ((double*)(ws + OFF_PAR))[cmb * NCHUNK + chunk] = smd[0];
}

// k5: prologue reduces the 36x56 partials to means (36 threads, LDS
// broadcast); then per l compute patch values + uncentered norms, then
// A[b][l][APAD] = (ip - muI)/nI ; B[b][9][L] and BT[b][l][APAD] = (rp - muR)/nR.
// No early return before the barrier (last block has inactive ids).
__global__ void k5_norm(float* __restrict__ ws) {
  __shared__ float smu[40];
  if (threadIdx.x < 36) {
    const double* par = (const double*)(ws + OFF_PAR);
    double s = 0.0;
    for (int c = 0; c < NCHUNK; ++c) s += par[threadIdx.x * NCHUNK + c];
    smu[threadIdx.x] = (float)(s / (double)L);
  }
  __syncthreads();
  int id = blockIdx.x * 256 + threadIdx.x;
  if (id >= 2 * L) return;
  int b = id / L, l = id % L;
  int i = l / NPATCH, j = l % NPATCH;
  const float* xg = ws + OFF_XG + ((size_t)b << 16);
  const float* rg = ws + OFF_REFG + ((size_t)b << 16);
  float vi[9], vr[9];
  float si = 0.f, sr = 0.f;
#pragma unroll
  for (int p = 0; p < 9; ++p) {
    int di = p / 3, dj = p % 3;
    vi[p] = xg[(2 * i + di) * PSZ + 2 * j + dj];
    vr[p] = rg[(2 * i + di) * PSZ + 2 * j + dj];
    si += vi[p] * vi[p];
    sr += vr[p] * vr[p];
  }
  float ni = sqrtf(si), nr = sqrtf(sr);
  float an[12], btn[12];
#pragma unroll
  for (int p = 0; p < 9; ++p) {
    float mi = smu[b * 9 + p];          // which=0 (input)
    float mr = smu[18 + b * 9 + p];     // which=1 (ref)
    float bn = (vr[p] - mr) / nr;
    an[p] = (vi[p] - mi) / ni;
    btn[p] = bn;
    ws[OFF_B + ((size_t)b * 9 + p) * L + l] = bn;
  }
  an[9] = an[10] = an[11] = 0.f;
  btn[9] = btn[10] = btn[11] = 0.f;
  float4* Ap4 = (float4*)(ws + OFF_A + (size_t)(b * L + l) * APAD);
  Ap4[0] = make_float4(an[0], an[1], an[2], an[3]);
  Ap4[1] = make_float4(an[4], an[5], an[6], an[7]);
  Ap4[2] = make_float4(an[8], an[9], an[10], an[11]);
  float4* Bt4 = (float4*)(ws + OFF_BT + (size_t)(b * L + l) * APAD);
  Bt4[0] = make_float4(btn[0], btn[1], btn[2], btn[3]);
  Bt4[1] = make_float4(btn[4], btn[5], btn[6], btn[7]);
  Bt4[2] = make_float4(btn[8], btn[9], btn[10], btn[11]);
}

// k6: FROZEN r13/r16 text (proven best: LDS broadcast, RPT=2, GRP=16,
// SEGLEN=512, 133.5-133.8 us, VGPR 40). Every deviation regressed:
// pk-math (r8), RPT=4 (r11), SMEM (r12), fn-pointer LDS (r15), GRP=32 (r17).
// grid: 2 x 32(rowblk) x 32(seg) = 2048 blocks (8/CU), 256 threads.
__global__ __launch_bounds__(TMAIN, 2) void k6_topk(float* __restrict__ ws) {
  __shared__ float lds[9 * MSTRIDE];  // 18432 B

  int bid = blockIdx.x;
  int seg = bid & (NS - 1);
  int rowblk = (bid >> 5) & (NROWBLK - 1);
  int b = bid >> 10;
  int m0 = seg << 9;
  int mend = m0 + SEGLEN;
  if (mend > L) mend = L;
  int mlen = mend - m0;

  const float* Bg = ws + OFF_B + (size_t)b * 9 * L + m0;
  for (int p = 0; p < 9; ++p)
    for (int mm = threadIdx.x; mm < mlen; mm += TMAIN)
      lds[p * MSTRIDE + mm] = Bg[(size_t)p * L + mm];
  __syncthreads();

  int row0 = rowblk * ROWS_PER_BLOCK + threadIdx.x * RPT;
  int r0 = row0 < L - 1 ? row0 : L - 1;
  int r1 = row0 + 1 < L - 1 ? row0 + 1 : L - 1;
  float a0[9], a1[9];
  {
    const float4* Ap0 = (const float4*)(ws + OFF_A + ((size_t)b * L + r0) * APAD);
    const float4* Ap1 = (const float4*)(ws + OFF_A + ((size_t)b * L + r1) * APAD);
    float4 u0 = Ap0[0], u1 = Ap0[1], u2 = Ap0[2];
    float4 w0 = Ap1[0], w1 = Ap1[1], w2 = Ap1[2];
    a0[0] = u0.x; a0[1] = u0.y; a0[2] = u0.z; a0[3] = u0.w;
    a0[4] = u1.x; a0[5] = u1.y; a0[6] = u1.z; a0[7] = u1.w; a0[8] = u2.x;
    a1[0] = w0.x; a1[1] = w0.y; a1[2] = w0.z; a1[3] = w0.w;
    a1[4] = w1.x; a1[5] = w1.y; a1[6] = w1.z; a1[7] = w1.w; a1[8] = w2.x;
  }

  float g00 = -FLT_MAX, g01 = g00, g02 = g00, g03 = g00;
  float g10 = g00, g11 = g00, g12 = g00, g13 = g00;
  int i00 = 0, i01 = 0, i02 = 0, i03 = 0;
  int i10 = 0, i11 = 0, i12 = 0, i13 = 0;

  int nfull = mlen >> 4;  // full groups of 16 (== 32 for segs 0..30)
  for (int g = 0; g < nfull; ++g) {
    int mm = g << 4;
    float rm0 = -FLT_MAX, rm1 = -FLT_MAX;
#pragma unroll
    for (int q = 0; q < 4; ++q) {
      float s00, s01, s02, s03, s10, s11, s12, s13;
#pragma unroll
      for (int p = 0; p < 9; ++p) {
        const float4 bq = *reinterpret_cast<const float4*>(&lds[p * MSTRIDE + mm + q * 4]);
        if (p == 0) {
          s00 = a0[0] * bq.x; s01 = a0[0] * bq.y; s02 = a0[0] * bq.z; s03 = a0[0] * bq.w;
          s10 = a1[0] * bq.x; s11 = a1[0] * bq.y; s12 = a1[0] * bq.z; s13 = a1[0] * bq.w;
        } else {
          s00 = fmaf(a0[p], bq.x, s00); s01 = fmaf(a0[p], bq.y, s01);
          s02 = fmaf(a0[p], bq.z, s02); s03 = fmaf(a0[p], bq.w, s03);
          s10 = fmaf(a1[p], bq.x, s10); s11 = fmaf(a1[p], bq.y, s11);
          s12 = fmaf(a1[p], bq.z, s12); s13 = fmaf(a1[p], bq.w, s13);
        }
      }
      rm0 = fmaxf(rm0, fmaxf(fmaxf(s00, s01), fmaxf(s02, s03)));
      rm1 = fmaxf(rm1, fmaxf(fmaxf(s10, s11), fmaxf(s12, s13)));
    }
    int gb = m0 + mm;
    insg(rm0, gb, g00, g01, g02, g03, i00, i01, i02, i03);
    insg(rm1, gb, g10, g11, g12, g13, i10, i11, i12, i13);
  }
  // tail (< 16 m, only the last segment has one)
  int tb = nfull << 4;
  if (tb < mlen) {
    float rt0 = -FLT_MAX, rt1 = -FLT_MAX;
    for (int mm = tb; mm < mlen; ++mm) {
      float bb = lds[mm];
      float sv0 = a0[0] * bb, sv1 = a1[0] * bb;
#pragma unroll
      for (int p = 1; p < 9; ++p) {
        bb = lds[p * MSTRIDE + mm];
        sv0 = fmaf(a0[p], bb, sv0); sv1 = fmaf(a1[p], bb, sv1);
      }
      rt0 = fmaxf(rt0, sv0); rt1 = fmaxf(rt1, sv1);
    }
    insg(rt0, m0 + tb, g00, g01, g02, g03, i00, i01, i02, i03);
    insg(rt1, m0 + tb, g10, g11, g12, g13, i10, i11, i12, i13);
  }

  int* wsi = (int*)ws;
  if (row0 < L) {
    size_t base = (((size_t)b * NS + seg) * ROWPAD + row0) * 4;
    ws[OFF_PV + base + 0] = g00; ws[OFF_PV + base + 1] = g01;
    ws[OFF_PV + base + 2] = g02; ws[OFF_PV + base + 3] = g03;
    wsi[OFF_PI + base + 0] = i00; wsi[OFF_PI + base + 1] = i01;
    wsi[OFF_PI + base + 2] = i02; wsi[OFF_PI + base + 3] = i03;
  }
  if (row0 + 1 < L) {
    size_t base = (((size_t)b * NS + seg) * ROWPAD + row0 + 1) * 4;
    ws[OFF_PV + base + 0] = g10; ws[OFF_PV + base + 1] = g11;
    ws[OFF_PV + base + 2] = g12; ws[OFF_PV + base + 3] = g13;
    wsi[OFF_PI + base + 0] = i10; wsi[OFF_PI + base + 1] = i11;
    wsi[OFF_PI + base + 2] = i12; wsi[OFF_PI + base + 3] = i13;
  }
}

// k7: per row, merge 32 segs x 4 (group-max, base) -> top-4 groups by
// (max desc, base asc), then rescan those groups with ranges CLIPPED TO THE
// SEGMENT END (disjoint -> no duplicates). BT rescan reads are 3x float4.
__global__ void k7_merge(float* __restrict__ ws) {
  int id = blockIdx.x * 256 + threadIdx.x;
  if (id >= 2 * L) return;
  int b = id / L, row = id % L;
  const int* wsi_c = (const int*)ws;

  float v0 = -FLT_MAX, v1 = v0, v2 = v0, v3 = v0;
  int x0 = 0x7FFFFFFF, x1 = x0, x2 = x0, x3 = x0;
  for (int s = 0; s < NS; ++s) {
    size_t base = (((size_t)b * NS + s) * ROWPAD + row) * 4;
#pragma unroll
    for (int q = 0; q < 4; ++q) {
      float val = ws[OFF_PV + base + q];
      int gb = wsi_c[OFF_PI + base + q];
      ins4c(val, gb, v0, v1, v2, v3, x0, x1, x2, x3);
    }
  }

  float a[9];
  {
    const float4* Ap4 = (const float4*)(ws + OFF_A + ((size_t)b * L + row) * APAD);
    float4 u0 = Ap4[0], u1 = Ap4[1], u2 = Ap4[2];
    a[0] = u0.x; a[1] = u0.y; a[2] = u0.z; a[3] = u0.w;
    a[4] = u1.x; a[5] = u1.y; a[6] = u1.z; a[7] = u1.w; a[8] = u2.x;
  }

  int gbs[4] = {x0, x1, x2, x3};
  float w0 = -FLT_MAX, w1 = w0, w2 = w0, w3 = w0;
  int y0 = 0x7FFFFFFF, y1 = y0, y2 = y0, y3 = y0;
#pragma unroll
  for (int slot = 0; slot < 4; ++slot) {
    int gb = gbs[slot];
    int se = ((gb >> 9) + 1) << 9;     // owning segment's end (SEGLEN = 512)
    int ge = gb + GRP;
    if (ge > se) ge = se;
    if (ge > L) ge = L;
    for (int mm = gb; mm < ge; ++mm) {
      const float4* bt4 = (const float4*)(ws + OFF_BT + ((size_t)b * L + mm) * APAD);
      float4 b0 = bt4[0], b1 = bt4[1], b2 = bt4[2];
      float s = a[0] * b0.x;
      s = fmaf(a[1], b0.y, s); s = fmaf(a[2], b0.z, s); s = fmaf(a[3], b0.w, s);
      s = fmaf(a[4], b1.x, s); s = fmaf(a[5], b1.y, s); s = fmaf(a[6], b1.z, s);
      s = fmaf(a[7], b1.w, s); s = fmaf(a[8], b2.x, s);
      ins4c(s, mm, w0, w1, w2, w3, y0, y1, y2, y3);
    }
  }
  int* wsi = (int*)ws;
  size_t ib = OFF_IDX + (size_t)id * 4;
  wsi[ib] = y0; wsi[ib + 1] = y1; wsi[ib + 2] = y2; wsi[ib + 3] = y3;
}

// k8: fold (overlap-add); one thread = one pixel x all 4 kk (IDX row read
// once as int4), reads ref_gray directly. grid 512 blocks.
__global__ void k8_fold(const float* __restrict__ ws, float* __restrict__ out) {
  int id = blockIdx.x * 256 + threadIdx.x;
  if (id >= 2 * PSZ * PSZ) return;
  int b = id >> 16;
  int pix = id & 0xFFFF;
  int y = pix >> 8, xx = pix & 255;
  const int* wsi = (const int*)ws;
  const float* rg = ws + OFF_REFG + ((size_t)b << 16);
  float acc0 = 0.f, acc1 = 0.f, acc2 = 0.f, acc3 = 0.f;
  for (int di = 0; di < 3; ++di) {
    int yy = y - di;
    if (yy < 0 || (yy & 1) || (yy >> 1) >= NPATCH) continue;
    int i = yy >> 1;
    for (int dj = 0; dj < 3; ++dj) {
      int xc = xx - dj;
      if (xc < 0 || (xc & 1) || (xc >> 1) >= NPATCH) continue;
      int j = xc >> 1;
      int l = i * NPATCH + j;
      const int4 m4 = *(const int4*)(wsi + OFF_IDX + ((size_t)b * L + l) * 4);
      acc0 += rg[(2 * (m4.x / NPATCH) + di) * PSZ + 2 * (m4.x % NPATCH) + dj];
      acc1 += rg[(2 * (m4.y / NPATCH) + di) * PSZ + 2 * (m4.y % NPATCH) + dj];
      acc2 += rg[(2 * (m4.z / NPATCH) + di) * PSZ + 2 * (m4.z % NPATCH) + dj];
      acc3 += rg[(2 * (m4.w / NPATCH) + di) * PSZ + 2 * (m4.w % NPATCH) + dj];
    }
  }
  float* ob = out + ((size_t)b * 7 + 3) * 65536 + pix;
  ob[0] = acc0;
  ob[65536] = acc1;
  ob[2 * 65536] = acc2;
  ob[3 * 65536] = acc3;
}

extern "C" void kernel_launch(void* const* d_in, const int* in_sizes, int n_in,
                              void* d_out, int out_size, void* d_ws, size_t ws_size,
                              hipStream_t stream) {
  const float* x = (const float*)d_in[0];
  const float* ref = (const float*)d_in[1];
  float* ws = (float*)d_ws;
  float* out = (float*)d_out;

  k12_gray<<<128, 256, 0, stream>>>(x, ref, ws, out);
  k4a_partial<<<36 * NCHUNK, TMAIN, 0, stream>>>(ws);
  k5_norm<<<(2 * L + 255) / 256, 256, 0, stream>>>(ws);
  k6_topk<<<2 * NROWBLK * NS, TMAIN, 0, stream>>>(ws);
  k7_merge<<<(2 * L + 255) / 256, 256, 0, stream>>>(ws);
  k8_fold<<<(2 * PSZ * PSZ + 255) / 256, 256, 0, stream>>>(ws, out);
}